// Round 14
// baseline (125.506 us; speedup 1.0000x reference)
//
#include <hip/hip_runtime.h>
#include <hip/hip_bf16.h>
#include <math.h>

// B=2, N=2048, DIM=1024, H=16, D=64; tokens M=4096; BH=32; K=1024
typedef __attribute__((ext_vector_type(8))) short short8v;     // 8 bf16
typedef __attribute__((ext_vector_type(4))) float f32x4;
typedef unsigned short ushort_t;

__device__ __forceinline__ ushort_t to_bf16(float v) {
    __hip_bfloat16 h = __float2bfloat16(v);
    return *(ushort_t*)&h;
}

// packed f32x2 -> bf16x2 (RNE), single instruction; low half = a
__device__ __forceinline__ unsigned cvt_pk_bf16(float a, float b) {
    unsigned r;
    asm("v_cvt_pk_bf16_f32 %0, %1, %2" : "=v"(r) : "v"(a), "v"(b));
    return r;
}

// fused 3-input max (clang folds nested fmaxf to v_max3_f32)
__device__ __forceinline__ float max3f(float a, float b, float c) {
    return fmaxf(fmaxf(a, b), c);
}

__device__ __forceinline__ void load_lds_16B(const void* g, void* l) {
    __builtin_amdgcn_global_load_lds(
        (__attribute__((address_space(1))) unsigned int*)(g),
        (__attribute__((address_space(3))) unsigned int*)(l), 16, 0, 0);
}

// ---------------------------------------------------------------------------
// Fused f32 -> bf16 conversion of x (4.19M), qkv_w (3.15M), proj_w (1.05M).
// ---------------------------------------------------------------------------
__global__ __launch_bounds__(256) void convert_kernel(
    const float* __restrict__ x, const float* __restrict__ wq,
    const float* __restrict__ wp, ushort_t* __restrict__ xb,
    ushort_t* __restrict__ wqb, ushort_t* __restrict__ wpb)
{
    int c = blockIdx.x * 256 + threadIdx.x;
    const float* src; ushort_t* dst; int base;
    if (c < 524288)      { src = x;  dst = xb;  base = c; }
    else if (c < 917504) { src = wq; dst = wqb; base = c - 524288; }
    else                 { src = wp; dst = wpb; base = c - 917504; }
    const float4* s4 = (const float4*)src;
    float4 a = s4[2 * (size_t)base], b = s4[2 * (size_t)base + 1];
    float vals[8] = {a.x, a.y, a.z, a.w, b.x, b.y, b.z, b.w};
    short8v o;
#pragma unroll
    for (int j = 0; j < 8; j++) o[j] = (short)to_bf16(vals[j]);
    *(short8v*)(dst + 8 * (size_t)base) = o;
}

// ---------------------------------------------------------------------------
// bf16 MFMA GEMM, m97 structure, BK=32.
// MODE 0: 1D grid 768, XCD-chunked; Q(x0.125*log2e)/K/V^T scatter.
// MODE 1: 2D grid; f32 C = A @ W^T + bias.
// ---------------------------------------------------------------------------
template <int MODE, int BM, int BN>
__global__ __launch_bounds__(256) void gemm_bf16_kernel(
    const ushort_t* __restrict__ A, const ushort_t* __restrict__ Bw,
    const float* __restrict__ bias, ushort_t* __restrict__ Qb,
    ushort_t* __restrict__ Kb, ushort_t* __restrict__ Vt,
    float* __restrict__ Cout)
{
    constexpr int MT = BM / 32, NT = BN / 32;
    __shared__ __align__(16) ushort_t As[BM * 32];
    __shared__ __align__(16) ushort_t Bs[BN * 32];
    const int t = threadIdx.x;
    const int w = t >> 6, l = t & 63;
    const int lo = l & 15, hi = l >> 4;
    const int wr = w >> 1, wc = w & 1;
    int m0, n0;
    if constexpr (MODE == 0) {
        // bijective XCD chunking: 768 blocks = 8 XCDs x 96
        int lin = (blockIdx.x & 7) * 96 + (blockIdx.x >> 3);
        m0 = (lin / 24) * BM;
        n0 = (lin % 24) * BN;
    } else {
        m0 = blockIdx.y * BM;
        n0 = blockIdx.x * BN;
    }
    const int K = 1024;

    const ushort_t* ga = A + (size_t)(m0 + (t >> 2)) * K + (t & 3) * 8;
    const ushort_t* gb = Bw + (size_t)(n0 + (t >> 2)) * K + (t & 3) * 8;

    f32x4 acc[MT][NT] = {};

    for (int k0 = 0; k0 < 1024; k0 += 32) {
#pragma unroll
        for (int i = 0; i < BM / 64; i++)
            load_lds_16B(ga + (size_t)(i * 64) * K + k0, As + (i * 256 + w * 64) * 8);
#pragma unroll
        for (int i = 0; i < BN / 64; i++)
            load_lds_16B(gb + (size_t)(i * 64) * K + k0, Bs + (i * 256 + w * 64) * 8);
        __syncthreads();

        short8v af[MT], bf[NT];
#pragma unroll
        for (int mt = 0; mt < MT; mt++) {
            int r = wr * (BM / 2) + mt * 16 + lo;
            af[mt] = *(const short8v*)&As[r * 32 + hi * 8];
        }
#pragma unroll
        for (int nt = 0; nt < NT; nt++) {
            int r = wc * (BN / 2) + nt * 16 + lo;
            bf[nt] = *(const short8v*)&Bs[r * 32 + hi * 8];
        }
#pragma unroll
        for (int mt = 0; mt < MT; mt++)
#pragma unroll
            for (int nt = 0; nt < NT; nt++)
                acc[mt][nt] = __builtin_amdgcn_mfma_f32_16x16x32_bf16(
                    af[mt], bf[nt], acc[mt][nt], 0, 0, 0);
        __syncthreads();
    }

#pragma unroll
    for (int mt = 0; mt < MT; mt++) {
#pragma unroll
        for (int nt = 0; nt < NT; nt++) {
            int col = n0 + wc * (BN / 2) + nt * 16 + lo;
            float bv = bias[col];
#pragma unroll
            for (int reg = 0; reg < 4; reg++) {
                int row = m0 + wr * (BM / 2) + mt * 16 + hi * 4 + reg;
                float val = acc[mt][nt][reg] + bv;
                if constexpr (MODE == 0) {
                    int bb = row >> 11, n = row & 2047;
                    int which = col >> 10, rem = col & 1023;
                    int h = rem >> 6, d = rem & 63;
                    int bh = bb * 16 + h;
                    if (which == 0)  // 0.125 * log2(e): softmax in exp2 domain
                        Qb[((size_t)bh * 2048 + n) * 64 + d] = to_bf16(val * 0.1803368601f);
                    else if (which == 1)
                        Kb[((size_t)bh * 2048 + n) * 64 + d] = to_bf16(val);
                    else
                        Vt[((size_t)bh * 64 + d) * 2048 + n] = to_bf16(val);
                } else {
                    Cout[(size_t)row * 1024 + col] = val;
                }
            }
        }
    }
}

// ---------------------------------------------------------------------------
// MFMA flash attention v8b (= verified round-12 v8 + max3 fmax tree).
// grid = 512 (XCD-swizzled), 4 waves x 32 q-rows (2 Q fragments/wave).
// Deferred-l (per-lane partials, epilogue reduce), branch-gated rescale,
// P in registers with permuted-column V, reg-staged K/V dbuf + async-stage,
// 1 barrier/tile.
// ---------------------------------------------------------------------------
__global__ __launch_bounds__(256) void attn_mfma_kernel(
    const ushort_t* __restrict__ Qg0, const ushort_t* __restrict__ Kg0,
    const ushort_t* __restrict__ Vg0, ushort_t* __restrict__ O)
{
    __shared__ __align__(16) ushort_t Ks[2 * 4096];  // [buf][key][d] swz
    __shared__ __align__(16) ushort_t Vs[2 * 4096];  // [buf][d][permuted k]

    const int t = threadIdx.x;
    const int l = t & 63, w = t >> 6;
    const int lo = l & 15, hi = l >> 4;
    const int lin = (blockIdx.x & 7) * 64 + (blockIdx.x >> 3);
    const int bh = lin >> 4;
    const int q0 = (lin & 15) * 128;
    const ushort_t* Qg = Qg0 + (size_t)bh * 2048 * 64;
    const ushort_t* Kg = Kg0 + (size_t)bh * 2048 * 64;
    const ushort_t* Vg = Vg0 + (size_t)bh * 64 * 2048;

    // Q B-fragments: wave covers queries q0 + w*32 + qf*16 + lo
    short8v aq[2][2];
#pragma unroll
    for (int qf = 0; qf < 2; qf++) {
        const ushort_t* qrow = Qg + (size_t)(q0 + w * 32 + qf * 16 + lo) * 64;
        aq[qf][0] = *(const short8v*)(qrow + hi * 8);
        aq[qf][1] = *(const short8v*)(qrow + 32 + hi * 8);
    }

    const int srow = t >> 3, sg = t & 7;
    const int sgs = sg ^ (srow & 7);
    const int gv0 = (sg >> 2) * 4 + (sg & 1) * 2;
    const int vo = ((sg >> 1) & 1) * 4;
    const int vswz0 = srow & 7;
    uint4 rk0, rk1, rv0, rv1;

    f32x4 o_acc[2][4] = {};
    float m_i[2] = {-INFINITY, -INFINITY};
    float lp[2] = {0.0f, 0.0f};   // per-lane PARTIAL l (own 16 keys)

    {
        rk0 = *(const uint4*)(Kg + (size_t)srow * 64 + sg * 8);
        rk1 = *(const uint4*)(Kg + (size_t)(srow + 32) * 64 + sg * 8);
        rv0 = *(const uint4*)(Vg + (size_t)srow * 2048 + sg * 8);
        rv1 = *(const uint4*)(Vg + (size_t)(srow + 32) * 2048 + sg * 8);
        *(uint4*)&Ks[srow * 64 + sgs * 8] = rk0;
        *(uint4*)&Ks[(srow + 32) * 64 + sgs * 8] = rk1;
        uint2 va0 = {rv0.x, rv0.y}, vb0 = {rv0.z, rv0.w};
        uint2 va1 = {rv1.x, rv1.y}, vb1 = {rv1.z, rv1.w};
        *(uint2*)&Vs[srow * 64 + (gv0 ^ vswz0) * 8 + vo] = va0;
        *(uint2*)&Vs[srow * 64 + ((gv0 + 1) ^ vswz0) * 8 + vo] = vb0;
        *(uint2*)&Vs[(srow + 32) * 64 + (gv0 ^ vswz0) * 8 + vo] = va1;
        *(uint2*)&Vs[(srow + 32) * 64 + ((gv0 + 1) ^ vswz0) * 8 + vo] = vb1;
    }
    __syncthreads();

    for (int kt = 0; kt < 32; kt++) {
        const int bufo = (kt & 1) * 4096;
        if (kt < 31) {
            const int k0n = (kt + 1) * 64;
            rk0 = *(const uint4*)(Kg + (size_t)(k0n + srow) * 64 + sg * 8);
            rk1 = *(const uint4*)(Kg + (size_t)(k0n + srow + 32) * 64 + sg * 8);
            rv0 = *(const uint4*)(Vg + (size_t)srow * 2048 + k0n + sg * 8);
            rv1 = *(const uint4*)(Vg + (size_t)(srow + 32) * 2048 + k0n + sg * 8);
        }

        // S^T = K @ Q^T : lane owns query qf*16+lo; keys nt*16 + hi*4 + reg.
        f32x4 s_acc[2][4];
        __builtin_amdgcn_s_setprio(1);
#pragma unroll
        for (int nt = 0; nt < 4; nt++) {
            f32x4 acc0 = {0.f, 0.f, 0.f, 0.f};
            f32x4 acc1 = {0.f, 0.f, 0.f, 0.f};
#pragma unroll
            for (int kk = 0; kk < 2; kk++) {
                int r = nt * 16 + lo;
                int g = (kk * 4 + hi) ^ (r & 7);
                short8v ak = *(const short8v*)&Ks[bufo + r * 64 + g * 8];
                acc0 = __builtin_amdgcn_mfma_f32_16x16x32_bf16(ak, aq[0][kk], acc0, 0, 0, 0);
                acc1 = __builtin_amdgcn_mfma_f32_16x16x32_bf16(ak, aq[1][kk], acc1, 0, 0, 0);
            }
            s_acc[0][nt] = acc0;
            s_acc[1][nt] = acc1;
        }
        __builtin_amdgcn_s_setprio(0);

        // per-fragment softmax: lane-local except the rare rescale branch
        short8v pa[2][2];
#pragma unroll
        for (int qf = 0; qf < 2; qf++) {
            float t0 = max3f(s_acc[qf][0][0], s_acc[qf][0][1], s_acc[qf][0][2]);
            float t1 = max3f(s_acc[qf][0][3], s_acc[qf][1][0], s_acc[qf][1][1]);
            float t2 = max3f(s_acc[qf][1][2], s_acc[qf][1][3], s_acc[qf][2][0]);
            float t3 = max3f(s_acc[qf][2][1], s_acc[qf][2][2], s_acc[qf][2][3]);
            float t4 = max3f(s_acc[qf][3][0], s_acc[qf][3][1], s_acc[qf][3][2]);
            float lmax = fmaxf(max3f(t0, t1, t2), max3f(t3, t4, s_acc[qf][3][3]));

            if (__any(lmax > m_i[qf] + 11.0f)) {   // same predicate as row-max
                float pm = fmaxf(lmax, __shfl_xor(lmax, 16));
                pm = fmaxf(pm, __shfl_xor(pm, 32));
                float mnew = fmaxf(m_i[qf], pm);
                float al = __builtin_amdgcn_exp2f(m_i[qf] - mnew);
                m_i[qf] = mnew;
                lp[qf] *= al;
                float a0 = __shfl(al, hi * 4 + 0);
                float a1 = __shfl(al, hi * 4 + 1);
                float a2 = __shfl(al, hi * 4 + 2);
                float a3 = __shfl(al, hi * 4 + 3);
#pragma unroll
                for (int dt = 0; dt < 4; dt++) {
                    o_acc[qf][dt][0] *= a0; o_acc[qf][dt][1] *= a1;
                    o_acc[qf][dt][2] *= a2; o_acc[qf][dt][3] *= a3;
                }
            }

            float ps = 0.0f;
#pragma unroll
            for (int nt = 0; nt < 4; nt++)
#pragma unroll
                for (int reg = 0; reg < 4; reg++) {
                    s_acc[qf][nt][reg] =
                        __builtin_amdgcn_exp2f(s_acc[qf][nt][reg] - m_i[qf]);
                    ps += s_acc[qf][nt][reg];
                }
            lp[qf] += ps;   // per-lane partial; cross-lane reduce in epilogue

            int4 w0i = {(int)cvt_pk_bf16(s_acc[qf][0][0], s_acc[qf][0][1]),
                        (int)cvt_pk_bf16(s_acc[qf][0][2], s_acc[qf][0][3]),
                        (int)cvt_pk_bf16(s_acc[qf][1][0], s_acc[qf][1][1]),
                        (int)cvt_pk_bf16(s_acc[qf][1][2], s_acc[qf][1][3])};
            int4 w1i = {(int)cvt_pk_bf16(s_acc[qf][2][0], s_acc[qf][2][1]),
                        (int)cvt_pk_bf16(s_acc[qf][2][2], s_acc[qf][2][3]),
                        (int)cvt_pk_bf16(s_acc[qf][3][0], s_acc[qf][3][1]),
                        (int)cvt_pk_bf16(s_acc[qf][3][2], s_acc[qf][3][3])};
            pa[qf][0] = __builtin_bit_cast(short8v, w0i);
            pa[qf][1] = __builtin_bit_cast(short8v, w1i);
        }

        if (kt < 31) {
            const int nxto = 4096 - bufo;
            *(uint4*)&Ks[nxto + srow * 64 + sgs * 8] = rk0;
            *(uint4*)&Ks[nxto + (srow + 32) * 64 + sgs * 8] = rk1;
            uint2 va0 = {rv0.x, rv0.y}, vb0 = {rv0.z, rv0.w};
            uint2 va1 = {rv1.x, rv1.y}, vb1 = {rv1.z, rv1.w};
            *(uint2*)&Vs[nxto + srow * 64 + (gv0 ^ vswz0) * 8 + vo] = va0;
            *(uint2*)&Vs[nxto + srow * 64 + ((gv0 + 1) ^ vswz0) * 8 + vo] = vb0;
            *(uint2*)&Vs[nxto + (srow + 32) * 64 + (gv0 ^ vswz0) * 8 + vo] = va1;
            *(uint2*)&Vs[nxto + (srow + 32) * 64 + ((gv0 + 1) ^ vswz0) * 8 + vo] = vb1;
        }

        // O += P @ V. Each bv read feeds both query fragments.
        __builtin_amdgcn_s_setprio(1);
#pragma unroll
        for (int dt = 0; dt < 4; dt++) {
            int r = dt * 16 + lo;
            short8v bv0 = *(const short8v*)&Vs[bufo + r * 64 + ((0 + hi) ^ (r & 7)) * 8];
            short8v bv1 = *(const short8v*)&Vs[bufo + r * 64 + ((4 + hi) ^ (r & 7)) * 8];
            o_acc[0][dt] = __builtin_amdgcn_mfma_f32_16x16x32_bf16(pa[0][0], bv0, o_acc[0][dt], 0, 0, 0);
            o_acc[0][dt] = __builtin_amdgcn_mfma_f32_16x16x32_bf16(pa[0][1], bv1, o_acc[0][dt], 0, 0, 0);
            o_acc[1][dt] = __builtin_amdgcn_mfma_f32_16x16x32_bf16(pa[1][0], bv0, o_acc[1][dt], 0, 0, 0);
            o_acc[1][dt] = __builtin_amdgcn_mfma_f32_16x16x32_bf16(pa[1][1], bv1, o_acc[1][dt], 0, 0, 0);
        }
        __builtin_amdgcn_s_setprio(0);
        __syncthreads();
    }

    // epilogue: reduce the partial l across the 4 row-lanes, then normalize
    const int b = bh >> 4, h = bh & 15;
#pragma unroll
    for (int qf = 0; qf < 2; qf++) {
        float ls = lp[qf];
        ls += __shfl_xor(ls, 16);
        ls += __shfl_xor(ls, 32);   // full l for query qf*16+lo, all lanes
#pragma unroll
        for (int reg = 0; reg < 4; reg++) {
            float lv = __shfl(ls, hi * 4 + reg);
            float inv = 1.0f / lv;
            int row = q0 + w * 32 + qf * 16 + hi * 4 + reg;
            ushort_t* orow = O + ((size_t)(b * 2048 + row)) * 1024 + h * 64;
#pragma unroll
            for (int dt = 0; dt < 4; dt++)
                orow[dt * 16 + lo] = to_bf16(o_acc[qf][dt][reg] * inv);
        }
    }
}

extern "C" void kernel_launch(void* const* d_in, const int* in_sizes, int n_in,
                              void* d_out, int out_size, void* d_ws, size_t ws_size,
                              hipStream_t stream) {
    const float* x      = (const float*)d_in[0];
    const float* qkv_w  = (const float*)d_in[1];
    const float* qkv_b  = (const float*)d_in[2];
    const float* proj_w = (const float*)d_in[3];
    const float* proj_b = (const float*)d_in[4];
    float* out = (float*)d_out;

    ushort_t* xb  = (ushort_t*)d_ws;        // 4,194,304  x bf16
    ushort_t* wqb = xb  + 4194304;          // 3,145,728  qkv_w bf16
    ushort_t* wpb = wqb + 3145728;          // 1,048,576  proj_w bf16
    ushort_t* qb  = wpb + 1048576;          // 4,194,304  Q (exp2-scaled)
    ushort_t* kb  = qb  + 4194304;          // 4,194,304  K
    ushort_t* vt  = kb  + 4194304;          // 4,194,304  V^T [BH][64][N]
    ushort_t* aob = vt  + 4194304;          // 4,194,304  attn out [M][1024]

    convert_kernel<<<4096, 256, 0, stream>>>(x, qkv_w, proj_w, xb, wqb, wpb);
    gemm_bf16_kernel<0, 128, 128><<<768, 256, 0, stream>>>(
        xb, wqb, qkv_b, qb, kb, vt, nullptr);
    attn_mfma_kernel<<<512, 256, 0, stream>>>(qb, kb, vt, aob);
    gemm_bf16_kernel<1, 128, 128><<<dim3(8, 32), 256, 0, stream>>>(
        aob, wpb, proj_b, nullptr, nullptr, nullptr, out);
}

// Round 15
// 119.465 us; speedup vs baseline: 1.0506x; 1.0506x over previous
//
#include <hip/hip_runtime.h>
#include <hip/hip_bf16.h>
#include <math.h>

// B=2, N=2048, DIM=1024, H=16, D=64; tokens M=4096; BH=32; K=1024
typedef __attribute__((ext_vector_type(8))) short short8v;     // 8 bf16
typedef __attribute__((ext_vector_type(4))) float f32x4;
typedef unsigned short ushort_t;

__device__ __forceinline__ ushort_t to_bf16(float v) {
    __hip_bfloat16 h = __float2bfloat16(v);
    return *(ushort_t*)&h;
}

// packed f32x2 -> bf16x2 (RNE), single instruction; low half = a
__device__ __forceinline__ unsigned cvt_pk_bf16(float a, float b) {
    unsigned r;
    asm("v_cvt_pk_bf16_f32 %0, %1, %2" : "=v"(r) : "v"(a), "v"(b));
    return r;
}

// fused 3-input max (clang folds nested fmaxf to v_max3_f32)
__device__ __forceinline__ float max3f(float a, float b, float c) {
    return fmaxf(fmaxf(a, b), c);
}

__device__ __forceinline__ void load_lds_16B(const void* g, void* l) {
    __builtin_amdgcn_global_load_lds(
        (__attribute__((address_space(1))) unsigned int*)(g),
        (__attribute__((address_space(3))) unsigned int*)(l), 16, 0, 0);
}

// ---------------------------------------------------------------------------
// Fused f32 -> bf16 conversion of x (4.19M), qkv_w (3.15M), proj_w (1.05M).
// ---------------------------------------------------------------------------
__global__ __launch_bounds__(256) void convert_kernel(
    const float* __restrict__ x, const float* __restrict__ wq,
    const float* __restrict__ wp, ushort_t* __restrict__ xb,
    ushort_t* __restrict__ wqb, ushort_t* __restrict__ wpb)
{
    int c = blockIdx.x * 256 + threadIdx.x;
    const float* src; ushort_t* dst; int base;
    if (c < 524288)      { src = x;  dst = xb;  base = c; }
    else if (c < 917504) { src = wq; dst = wqb; base = c - 524288; }
    else                 { src = wp; dst = wpb; base = c - 917504; }
    const float4* s4 = (const float4*)src;
    float4 a = s4[2 * (size_t)base], b = s4[2 * (size_t)base + 1];
    float vals[8] = {a.x, a.y, a.z, a.w, b.x, b.y, b.z, b.w};
    short8v o;
#pragma unroll
    for (int j = 0; j < 8; j++) o[j] = (short)to_bf16(vals[j]);
    *(short8v*)(dst + 8 * (size_t)base) = o;
}

// ---------------------------------------------------------------------------
// bf16 MFMA GEMM, m97 structure, BK=32.
// MODE 0: 1D grid 768, XCD-chunked; Q(x0.125*log2e)/K/V^T scatter.
// MODE 1: 2D grid; f32 C = A @ W^T + bias.
// ---------------------------------------------------------------------------
template <int MODE, int BM, int BN>
__global__ __launch_bounds__(256) void gemm_bf16_kernel(
    const ushort_t* __restrict__ A, const ushort_t* __restrict__ Bw,
    const float* __restrict__ bias, ushort_t* __restrict__ Qb,
    ushort_t* __restrict__ Kb, ushort_t* __restrict__ Vt,
    float* __restrict__ Cout)
{
    constexpr int MT = BM / 32, NT = BN / 32;
    __shared__ __align__(16) ushort_t As[BM * 32];
    __shared__ __align__(16) ushort_t Bs[BN * 32];
    const int t = threadIdx.x;
    const int w = t >> 6, l = t & 63;
    const int lo = l & 15, hi = l >> 4;
    const int wr = w >> 1, wc = w & 1;
    int m0, n0;
    if constexpr (MODE == 0) {
        // bijective XCD chunking: 768 blocks = 8 XCDs x 96
        int lin = (blockIdx.x & 7) * 96 + (blockIdx.x >> 3);
        m0 = (lin / 24) * BM;
        n0 = (lin % 24) * BN;
    } else {
        m0 = blockIdx.y * BM;
        n0 = blockIdx.x * BN;
    }
    const int K = 1024;

    const ushort_t* ga = A + (size_t)(m0 + (t >> 2)) * K + (t & 3) * 8;
    const ushort_t* gb = Bw + (size_t)(n0 + (t >> 2)) * K + (t & 3) * 8;

    f32x4 acc[MT][NT] = {};

    for (int k0 = 0; k0 < 1024; k0 += 32) {
#pragma unroll
        for (int i = 0; i < BM / 64; i++)
            load_lds_16B(ga + (size_t)(i * 64) * K + k0, As + (i * 256 + w * 64) * 8);
#pragma unroll
        for (int i = 0; i < BN / 64; i++)
            load_lds_16B(gb + (size_t)(i * 64) * K + k0, Bs + (i * 256 + w * 64) * 8);
        __syncthreads();

        short8v af[MT], bf[NT];
#pragma unroll
        for (int mt = 0; mt < MT; mt++) {
            int r = wr * (BM / 2) + mt * 16 + lo;
            af[mt] = *(const short8v*)&As[r * 32 + hi * 8];
        }
#pragma unroll
        for (int nt = 0; nt < NT; nt++) {
            int r = wc * (BN / 2) + nt * 16 + lo;
            bf[nt] = *(const short8v*)&Bs[r * 32 + hi * 8];
        }
#pragma unroll
        for (int mt = 0; mt < MT; mt++)
#pragma unroll
            for (int nt = 0; nt < NT; nt++)
                acc[mt][nt] = __builtin_amdgcn_mfma_f32_16x16x32_bf16(
                    af[mt], bf[nt], acc[mt][nt], 0, 0, 0);
        __syncthreads();
    }

#pragma unroll
    for (int mt = 0; mt < MT; mt++) {
#pragma unroll
        for (int nt = 0; nt < NT; nt++) {
            int col = n0 + wc * (BN / 2) + nt * 16 + lo;
            float bv = bias[col];
#pragma unroll
            for (int reg = 0; reg < 4; reg++) {
                int row = m0 + wr * (BM / 2) + mt * 16 + hi * 4 + reg;
                float val = acc[mt][nt][reg] + bv;
                if constexpr (MODE == 0) {
                    int bb = row >> 11, n = row & 2047;
                    int which = col >> 10, rem = col & 1023;
                    int h = rem >> 6, d = rem & 63;
                    int bh = bb * 16 + h;
                    if (which == 0)  // 0.125 * log2(e): softmax in exp2 domain
                        Qb[((size_t)bh * 2048 + n) * 64 + d] = to_bf16(val * 0.1803368601f);
                    else if (which == 1)
                        Kb[((size_t)bh * 2048 + n) * 64 + d] = to_bf16(val);
                    else
                        Vt[((size_t)bh * 64 + d) * 2048 + n] = to_bf16(val);
                } else {
                    Cout[(size_t)row * 1024 + col] = val;
                }
            }
        }
    }
}

// ---------------------------------------------------------------------------
// MFMA flash attention v8b (verified round-14: v8 + max3 fmax tree).
// grid = 512 (XCD-swizzled), 4 waves x 32 q-rows (2 Q fragments/wave).
// Deferred-l (per-lane partials, epilogue reduce), branch-gated rescale,
// P in registers with permuted-column V, reg-staged K/V dbuf + async-stage,
// 1 barrier/tile.
// ---------------------------------------------------------------------------
__global__ __launch_bounds__(256) void attn_mfma_kernel(
    const ushort_t* __restrict__ Qg0, const ushort_t* __restrict__ Kg0,
    const ushort_t* __restrict__ Vg0, ushort_t* __restrict__ O)
{
    __shared__ __align__(16) ushort_t Ks[2 * 4096];  // [buf][key][d] swz
    __shared__ __align__(16) ushort_t Vs[2 * 4096];  // [buf][d][permuted k]

    const int t = threadIdx.x;
    const int l = t & 63, w = t >> 6;
    const int lo = l & 15, hi = l >> 4;
    const int lin = (blockIdx.x & 7) * 64 + (blockIdx.x >> 3);
    const int bh = lin >> 4;
    const int q0 = (lin & 15) * 128;
    const ushort_t* Qg = Qg0 + (size_t)bh * 2048 * 64;
    const ushort_t* Kg = Kg0 + (size_t)bh * 2048 * 64;
    const ushort_t* Vg = Vg0 + (size_t)bh * 64 * 2048;

    // Q B-fragments: wave covers queries q0 + w*32 + qf*16 + lo
    short8v aq[2][2];
#pragma unroll
    for (int qf = 0; qf < 2; qf++) {
        const ushort_t* qrow = Qg + (size_t)(q0 + w * 32 + qf * 16 + lo) * 64;
        aq[qf][0] = *(const short8v*)(qrow + hi * 8);
        aq[qf][1] = *(const short8v*)(qrow + 32 + hi * 8);
    }

    const int srow = t >> 3, sg = t & 7;
    const int sgs = sg ^ (srow & 7);
    const int gv0 = (sg >> 2) * 4 + (sg & 1) * 2;
    const int vo = ((sg >> 1) & 1) * 4;
    const int vswz0 = srow & 7;
    uint4 rk0, rk1, rv0, rv1;

    f32x4 o_acc[2][4] = {};
    float m_i[2] = {-INFINITY, -INFINITY};
    float lp[2] = {0.0f, 0.0f};   // per-lane PARTIAL l (own 16 keys)

    {
        rk0 = *(const uint4*)(Kg + (size_t)srow * 64 + sg * 8);
        rk1 = *(const uint4*)(Kg + (size_t)(srow + 32) * 64 + sg * 8);
        rv0 = *(const uint4*)(Vg + (size_t)srow * 2048 + sg * 8);
        rv1 = *(const uint4*)(Vg + (size_t)(srow + 32) * 2048 + sg * 8);
        *(uint4*)&Ks[srow * 64 + sgs * 8] = rk0;
        *(uint4*)&Ks[(srow + 32) * 64 + sgs * 8] = rk1;
        uint2 va0 = {rv0.x, rv0.y}, vb0 = {rv0.z, rv0.w};
        uint2 va1 = {rv1.x, rv1.y}, vb1 = {rv1.z, rv1.w};
        *(uint2*)&Vs[srow * 64 + (gv0 ^ vswz0) * 8 + vo] = va0;
        *(uint2*)&Vs[srow * 64 + ((gv0 + 1) ^ vswz0) * 8 + vo] = vb0;
        *(uint2*)&Vs[(srow + 32) * 64 + (gv0 ^ vswz0) * 8 + vo] = va1;
        *(uint2*)&Vs[(srow + 32) * 64 + ((gv0 + 1) ^ vswz0) * 8 + vo] = vb1;
    }
    __syncthreads();

    for (int kt = 0; kt < 32; kt++) {
        const int bufo = (kt & 1) * 4096;
        if (kt < 31) {
            const int k0n = (kt + 1) * 64;
            rk0 = *(const uint4*)(Kg + (size_t)(k0n + srow) * 64 + sg * 8);
            rk1 = *(const uint4*)(Kg + (size_t)(k0n + srow + 32) * 64 + sg * 8);
            rv0 = *(const uint4*)(Vg + (size_t)srow * 2048 + k0n + sg * 8);
            rv1 = *(const uint4*)(Vg + (size_t)(srow + 32) * 2048 + k0n + sg * 8);
        }

        // S^T = K @ Q^T : lane owns query qf*16+lo; keys nt*16 + hi*4 + reg.
        f32x4 s_acc[2][4];
        __builtin_amdgcn_s_setprio(1);
#pragma unroll
        for (int nt = 0; nt < 4; nt++) {
            f32x4 acc0 = {0.f, 0.f, 0.f, 0.f};
            f32x4 acc1 = {0.f, 0.f, 0.f, 0.f};
#pragma unroll
            for (int kk = 0; kk < 2; kk++) {
                int r = nt * 16 + lo;
                int g = (kk * 4 + hi) ^ (r & 7);
                short8v ak = *(const short8v*)&Ks[bufo + r * 64 + g * 8];
                acc0 = __builtin_amdgcn_mfma_f32_16x16x32_bf16(ak, aq[0][kk], acc0, 0, 0, 0);
                acc1 = __builtin_amdgcn_mfma_f32_16x16x32_bf16(ak, aq[1][kk], acc1, 0, 0, 0);
            }
            s_acc[0][nt] = acc0;
            s_acc[1][nt] = acc1;
        }
        __builtin_amdgcn_s_setprio(0);

        // per-fragment softmax: lane-local except the rare rescale branch
        short8v pa[2][2];
#pragma unroll
        for (int qf = 0; qf < 2; qf++) {
            float t0 = max3f(s_acc[qf][0][0], s_acc[qf][0][1], s_acc[qf][0][2]);
            float t1 = max3f(s_acc[qf][0][3], s_acc[qf][1][0], s_acc[qf][1][1]);
            float t2 = max3f(s_acc[qf][1][2], s_acc[qf][1][3], s_acc[qf][2][0]);
            float t3 = max3f(s_acc[qf][2][1], s_acc[qf][2][2], s_acc[qf][2][3]);
            float t4 = max3f(s_acc[qf][3][0], s_acc[qf][3][1], s_acc[qf][3][2]);
            float lmax = fmaxf(max3f(t0, t1, t2), max3f(t3, t4, s_acc[qf][3][3]));

            if (__any(lmax > m_i[qf] + 11.0f)) {   // same predicate as row-max
                float pm = fmaxf(lmax, __shfl_xor(lmax, 16));
                pm = fmaxf(pm, __shfl_xor(pm, 32));
                float mnew = fmaxf(m_i[qf], pm);
                float al = __builtin_amdgcn_exp2f(m_i[qf] - mnew);
                m_i[qf] = mnew;
                lp[qf] *= al;
                float a0 = __shfl(al, hi * 4 + 0);
                float a1 = __shfl(al, hi * 4 + 1);
                float a2 = __shfl(al, hi * 4 + 2);
                float a3 = __shfl(al, hi * 4 + 3);
#pragma unroll
                for (int dt = 0; dt < 4; dt++) {
                    o_acc[qf][dt][0] *= a0; o_acc[qf][dt][1] *= a1;
                    o_acc[qf][dt][2] *= a2; o_acc[qf][dt][3] *= a3;
                }
            }

            float ps = 0.0f;
#pragma unroll
            for (int nt = 0; nt < 4; nt++)
#pragma unroll
                for (int reg = 0; reg < 4; reg++) {
                    s_acc[qf][nt][reg] =
                        __builtin_amdgcn_exp2f(s_acc[qf][nt][reg] - m_i[qf]);
                    ps += s_acc[qf][nt][reg];
                }
            lp[qf] += ps;   // per-lane partial; cross-lane reduce in epilogue

            int4 w0i = {(int)cvt_pk_bf16(s_acc[qf][0][0], s_acc[qf][0][1]),
                        (int)cvt_pk_bf16(s_acc[qf][0][2], s_acc[qf][0][3]),
                        (int)cvt_pk_bf16(s_acc[qf][1][0], s_acc[qf][1][1]),
                        (int)cvt_pk_bf16(s_acc[qf][1][2], s_acc[qf][1][3])};
            int4 w1i = {(int)cvt_pk_bf16(s_acc[qf][2][0], s_acc[qf][2][1]),
                        (int)cvt_pk_bf16(s_acc[qf][2][2], s_acc[qf][2][3]),
                        (int)cvt_pk_bf16(s_acc[qf][3][0], s_acc[qf][3][1]),
                        (int)cvt_pk_bf16(s_acc[qf][3][2], s_acc[qf][3][3])};
            pa[qf][0] = __builtin_bit_cast(short8v, w0i);
            pa[qf][1] = __builtin_bit_cast(short8v, w1i);
        }

        if (kt < 31) {
            const int nxto = 4096 - bufo;
            *(uint4*)&Ks[nxto + srow * 64 + sgs * 8] = rk0;
            *(uint4*)&Ks[nxto + (srow + 32) * 64 + sgs * 8] = rk1;
            uint2 va0 = {rv0.x, rv0.y}, vb0 = {rv0.z, rv0.w};
            uint2 va1 = {rv1.x, rv1.y}, vb1 = {rv1.z, rv1.w};
            *(uint2*)&Vs[nxto + srow * 64 + (gv0 ^ vswz0) * 8 + vo] = va0;
            *(uint2*)&Vs[nxto + srow * 64 + ((gv0 + 1) ^ vswz0) * 8 + vo] = vb0;
            *(uint2*)&Vs[nxto + (srow + 32) * 64 + (gv0 ^ vswz0) * 8 + vo] = va1;
            *(uint2*)&Vs[nxto + (srow + 32) * 64 + ((gv0 + 1) ^ vswz0) * 8 + vo] = vb1;
        }

        // O += P @ V. Each bv read feeds both query fragments.
        __builtin_amdgcn_s_setprio(1);
#pragma unroll
        for (int dt = 0; dt < 4; dt++) {
            int r = dt * 16 + lo;
            short8v bv0 = *(const short8v*)&Vs[bufo + r * 64 + ((0 + hi) ^ (r & 7)) * 8];
            short8v bv1 = *(const short8v*)&Vs[bufo + r * 64 + ((4 + hi) ^ (r & 7)) * 8];
            o_acc[0][dt] = __builtin_amdgcn_mfma_f32_16x16x32_bf16(pa[0][0], bv0, o_acc[0][dt], 0, 0, 0);
            o_acc[0][dt] = __builtin_amdgcn_mfma_f32_16x16x32_bf16(pa[0][1], bv1, o_acc[0][dt], 0, 0, 0);
            o_acc[1][dt] = __builtin_amdgcn_mfma_f32_16x16x32_bf16(pa[1][0], bv0, o_acc[1][dt], 0, 0, 0);
            o_acc[1][dt] = __builtin_amdgcn_mfma_f32_16x16x32_bf16(pa[1][1], bv1, o_acc[1][dt], 0, 0, 0);
        }
        __builtin_amdgcn_s_setprio(0);
        __syncthreads();
    }

    // epilogue: reduce the partial l across the 4 row-lanes, then normalize
    const int b = bh >> 4, h = bh & 15;
#pragma unroll
    for (int qf = 0; qf < 2; qf++) {
        float ls = lp[qf];
        ls += __shfl_xor(ls, 16);
        ls += __shfl_xor(ls, 32);   // full l for query qf*16+lo, all lanes
#pragma unroll
        for (int reg = 0; reg < 4; reg++) {
            float lv = __shfl(ls, hi * 4 + reg);
            float inv = 1.0f / lv;
            int row = q0 + w * 32 + qf * 16 + hi * 4 + reg;
            ushort_t* orow = O + ((size_t)(b * 2048 + row)) * 1024 + h * 64;
#pragma unroll
            for (int dt = 0; dt < 4; dt++)
                orow[dt * 16 + lo] = to_bf16(o_acc[qf][dt][reg] * inv);
        }
    }
}

extern "C" void kernel_launch(void* const* d_in, const int* in_sizes, int n_in,
                              void* d_out, int out_size, void* d_ws, size_t ws_size,
                              hipStream_t stream) {
    const float* x      = (const float*)d_in[0];
    const float* qkv_w  = (const float*)d_in[1];
    const float* qkv_b  = (const float*)d_in[2];
    const float* proj_w = (const float*)d_in[3];
    const float* proj_b = (const float*)d_in[4];
    float* out = (float*)d_out;

    ushort_t* xb  = (ushort_t*)d_ws;        // 4,194,304  x bf16
    ushort_t* wqb = xb  + 4194304;          // 3,145,728  qkv_w bf16
    ushort_t* wpb = wqb + 3145728;          // 1,048,576  proj_w bf16
    ushort_t* qb  = wpb + 1048576;          // 4,194,304  Q (exp2-scaled)
    ushort_t* kb  = qb  + 4194304;          // 4,194,304  K
    ushort_t* vt  = kb  + 4194304;          // 4,194,304  V^T [BH][64][N]
    ushort_t* aob = vt  + 4194304;          // 4,194,304  attn out [M][1024]

    convert_kernel<<<4096, 256, 0, stream>>>(x, qkv_w, proj_w, xb, wqb, wpb);
    gemm_bf16_kernel<0, 128, 128><<<768, 256, 0, stream>>>(
        xb, wqb, qkv_b, qb, kb, vt, nullptr);
    attn_mfma_kernel<<<512, 256, 0, stream>>>(qb, kb, vt, aob);
    gemm_bf16_kernel<1, 64, 128><<<dim3(8, 64), 256, 0, stream>>>(
        aob, wpb, proj_b, nullptr, nullptr, nullptr, out);
}

// Round 16
// 116.697 us; speedup vs baseline: 1.0755x; 1.0237x over previous
//
#include <hip/hip_runtime.h>
#include <hip/hip_bf16.h>
#include <math.h>

// B=2, N=2048, DIM=1024, H=16, D=64; tokens M=4096; BH=32; K=1024
typedef __attribute__((ext_vector_type(8))) short short8v;     // 8 bf16
typedef __attribute__((ext_vector_type(4))) float f32x4;
typedef unsigned short ushort_t;

__device__ __forceinline__ ushort_t to_bf16(float v) {
    __hip_bfloat16 h = __float2bfloat16(v);
    return *(ushort_t*)&h;
}

// packed f32x2 -> bf16x2 (RNE), single instruction; low half = a
__device__ __forceinline__ unsigned cvt_pk_bf16(float a, float b) {
    unsigned r;
    asm("v_cvt_pk_bf16_f32 %0, %1, %2" : "=v"(r) : "v"(a), "v"(b));
    return r;
}

// fused 3-input max (clang folds nested fmaxf to v_max3_f32)
__device__ __forceinline__ float max3f(float a, float b, float c) {
    return fmaxf(fmaxf(a, b), c);
}

__device__ __forceinline__ void load_lds_16B(const void* g, void* l) {
    __builtin_amdgcn_global_load_lds(
        (__attribute__((address_space(1))) unsigned int*)(g),
        (__attribute__((address_space(3))) unsigned int*)(l), 16, 0, 0);
}

// ---------------------------------------------------------------------------
// Fused f32 -> bf16 conversion of x (4.19M), qkv_w (3.15M), proj_w (1.05M).
// ---------------------------------------------------------------------------
__global__ __launch_bounds__(256) void convert_kernel(
    const float* __restrict__ x, const float* __restrict__ wq,
    const float* __restrict__ wp, ushort_t* __restrict__ xb,
    ushort_t* __restrict__ wqb, ushort_t* __restrict__ wpb)
{
    int c = blockIdx.x * 256 + threadIdx.x;
    const float* src; ushort_t* dst; int base;
    if (c < 524288)      { src = x;  dst = xb;  base = c; }
    else if (c < 917504) { src = wq; dst = wqb; base = c - 524288; }
    else                 { src = wp; dst = wpb; base = c - 917504; }
    const float4* s4 = (const float4*)src;
    float4 a = s4[2 * (size_t)base], b = s4[2 * (size_t)base + 1];
    float vals[8] = {a.x, a.y, a.z, a.w, b.x, b.y, b.z, b.w};
    short8v o;
#pragma unroll
    for (int j = 0; j < 8; j++) o[j] = (short)to_bf16(vals[j]);
    *(short8v*)(dst + 8 * (size_t)base) = o;
}

// ---------------------------------------------------------------------------
// bf16 MFMA GEMM, m97 structure, BK=32.
// MODE 0: 1D grid 768, XCD-chunked; Q(x0.125*log2e)/K/V^T scatter.
// MODE 1: 2D grid; f32 C = A @ W^T + bias.
// ---------------------------------------------------------------------------
template <int MODE, int BM, int BN>
__global__ __launch_bounds__(256) void gemm_bf16_kernel(
    const ushort_t* __restrict__ A, const ushort_t* __restrict__ Bw,
    const float* __restrict__ bias, ushort_t* __restrict__ Qb,
    ushort_t* __restrict__ Kb, ushort_t* __restrict__ Vt,
    float* __restrict__ Cout)
{
    constexpr int MT = BM / 32, NT = BN / 32;
    __shared__ __align__(16) ushort_t As[BM * 32];
    __shared__ __align__(16) ushort_t Bs[BN * 32];
    const int t = threadIdx.x;
    const int w = t >> 6, l = t & 63;
    const int lo = l & 15, hi = l >> 4;
    const int wr = w >> 1, wc = w & 1;
    int m0, n0;
    if constexpr (MODE == 0) {
        // bijective XCD chunking: 768 blocks = 8 XCDs x 96
        int lin = (blockIdx.x & 7) * 96 + (blockIdx.x >> 3);
        m0 = (lin / 24) * BM;
        n0 = (lin % 24) * BN;
    } else {
        m0 = blockIdx.y * BM;
        n0 = blockIdx.x * BN;
    }
    const int K = 1024;

    const ushort_t* ga = A + (size_t)(m0 + (t >> 2)) * K + (t & 3) * 8;
    const ushort_t* gb = Bw + (size_t)(n0 + (t >> 2)) * K + (t & 3) * 8;

    f32x4 acc[MT][NT] = {};

    for (int k0 = 0; k0 < 1024; k0 += 32) {
#pragma unroll
        for (int i = 0; i < BM / 64; i++)
            load_lds_16B(ga + (size_t)(i * 64) * K + k0, As + (i * 256 + w * 64) * 8);
#pragma unroll
        for (int i = 0; i < BN / 64; i++)
            load_lds_16B(gb + (size_t)(i * 64) * K + k0, Bs + (i * 256 + w * 64) * 8);
        __syncthreads();

        short8v af[MT], bf[NT];
#pragma unroll
        for (int mt = 0; mt < MT; mt++) {
            int r = wr * (BM / 2) + mt * 16 + lo;
            af[mt] = *(const short8v*)&As[r * 32 + hi * 8];
        }
#pragma unroll
        for (int nt = 0; nt < NT; nt++) {
            int r = wc * (BN / 2) + nt * 16 + lo;
            bf[nt] = *(const short8v*)&Bs[r * 32 + hi * 8];
        }
#pragma unroll
        for (int mt = 0; mt < MT; mt++)
#pragma unroll
            for (int nt = 0; nt < NT; nt++)
                acc[mt][nt] = __builtin_amdgcn_mfma_f32_16x16x32_bf16(
                    af[mt], bf[nt], acc[mt][nt], 0, 0, 0);
        __syncthreads();
    }

#pragma unroll
    for (int mt = 0; mt < MT; mt++) {
#pragma unroll
        for (int nt = 0; nt < NT; nt++) {
            int col = n0 + wc * (BN / 2) + nt * 16 + lo;
            float bv = bias[col];
#pragma unroll
            for (int reg = 0; reg < 4; reg++) {
                int row = m0 + wr * (BM / 2) + mt * 16 + hi * 4 + reg;
                float val = acc[mt][nt][reg] + bv;
                if constexpr (MODE == 0) {
                    int bb = row >> 11, n = row & 2047;
                    int which = col >> 10, rem = col & 1023;
                    int h = rem >> 6, d = rem & 63;
                    int bh = bb * 16 + h;
                    if (which == 0)  // 0.125 * log2(e): softmax in exp2 domain
                        Qb[((size_t)bh * 2048 + n) * 64 + d] = to_bf16(val * 0.1803368601f);
                    else if (which == 1)
                        Kb[((size_t)bh * 2048 + n) * 64 + d] = to_bf16(val);
                    else
                        Vt[((size_t)bh * 64 + d) * 2048 + n] = to_bf16(val);
                } else {
                    Cout[(size_t)row * 1024 + col] = val;
                }
            }
        }
    }
}

// ---------------------------------------------------------------------------
// MFMA flash attention v8c: v8b + __launch_bounds__(256, 2).
// grid 512 caps occupancy at 2 waves/SIMD regardless (work-shaped:
// 2048 waves total), so targeting 2 waves/EU unlocks the full register
// budget for the scheduler at ZERO occupancy cost.
// grid = 512 (XCD-swizzled), 4 waves x 32 q-rows (2 Q fragments/wave).
// Deferred-l, branch-gated rescale, P in registers, permuted-column V,
// reg-staged K/V dbuf + async-stage, 1 barrier/tile, max3 fmax tree.
// ---------------------------------------------------------------------------
__global__ __launch_bounds__(256, 2) void attn_mfma_kernel(
    const ushort_t* __restrict__ Qg0, const ushort_t* __restrict__ Kg0,
    const ushort_t* __restrict__ Vg0, ushort_t* __restrict__ O)
{
    __shared__ __align__(16) ushort_t Ks[2 * 4096];  // [buf][key][d] swz
    __shared__ __align__(16) ushort_t Vs[2 * 4096];  // [buf][d][permuted k]

    const int t = threadIdx.x;
    const int l = t & 63, w = t >> 6;
    const int lo = l & 15, hi = l >> 4;
    const int lin = (blockIdx.x & 7) * 64 + (blockIdx.x >> 3);
    const int bh = lin >> 4;
    const int q0 = (lin & 15) * 128;
    const ushort_t* Qg = Qg0 + (size_t)bh * 2048 * 64;
    const ushort_t* Kg = Kg0 + (size_t)bh * 2048 * 64;
    const ushort_t* Vg = Vg0 + (size_t)bh * 64 * 2048;

    // Q B-fragments: wave covers queries q0 + w*32 + qf*16 + lo
    short8v aq[2][2];
#pragma unroll
    for (int qf = 0; qf < 2; qf++) {
        const ushort_t* qrow = Qg + (size_t)(q0 + w * 32 + qf * 16 + lo) * 64;
        aq[qf][0] = *(const short8v*)(qrow + hi * 8);
        aq[qf][1] = *(const short8v*)(qrow + 32 + hi * 8);
    }

    const int srow = t >> 3, sg = t & 7;
    const int sgs = sg ^ (srow & 7);
    const int gv0 = (sg >> 2) * 4 + (sg & 1) * 2;
    const int vo = ((sg >> 1) & 1) * 4;
    const int vswz0 = srow & 7;
    uint4 rk0, rk1, rv0, rv1;

    f32x4 o_acc[2][4] = {};
    float m_i[2] = {-INFINITY, -INFINITY};
    float lp[2] = {0.0f, 0.0f};   // per-lane PARTIAL l (own 16 keys)

    {
        rk0 = *(const uint4*)(Kg + (size_t)srow * 64 + sg * 8);
        rk1 = *(const uint4*)(Kg + (size_t)(srow + 32) * 64 + sg * 8);
        rv0 = *(const uint4*)(Vg + (size_t)srow * 2048 + sg * 8);
        rv1 = *(const uint4*)(Vg + (size_t)(srow + 32) * 2048 + sg * 8);
        *(uint4*)&Ks[srow * 64 + sgs * 8] = rk0;
        *(uint4*)&Ks[(srow + 32) * 64 + sgs * 8] = rk1;
        uint2 va0 = {rv0.x, rv0.y}, vb0 = {rv0.z, rv0.w};
        uint2 va1 = {rv1.x, rv1.y}, vb1 = {rv1.z, rv1.w};
        *(uint2*)&Vs[srow * 64 + (gv0 ^ vswz0) * 8 + vo] = va0;
        *(uint2*)&Vs[srow * 64 + ((gv0 + 1) ^ vswz0) * 8 + vo] = vb0;
        *(uint2*)&Vs[(srow + 32) * 64 + (gv0 ^ vswz0) * 8 + vo] = va1;
        *(uint2*)&Vs[(srow + 32) * 64 + ((gv0 + 1) ^ vswz0) * 8 + vo] = vb1;
    }
    __syncthreads();

    for (int kt = 0; kt < 32; kt++) {
        const int bufo = (kt & 1) * 4096;
        if (kt < 31) {
            const int k0n = (kt + 1) * 64;
            rk0 = *(const uint4*)(Kg + (size_t)(k0n + srow) * 64 + sg * 8);
            rk1 = *(const uint4*)(Kg + (size_t)(k0n + srow + 32) * 64 + sg * 8);
            rv0 = *(const uint4*)(Vg + (size_t)srow * 2048 + k0n + sg * 8);
            rv1 = *(const uint4*)(Vg + (size_t)(srow + 32) * 2048 + k0n + sg * 8);
        }

        // S^T = K @ Q^T : lane owns query qf*16+lo; keys nt*16 + hi*4 + reg.
        f32x4 s_acc[2][4];
        __builtin_amdgcn_s_setprio(1);
#pragma unroll
        for (int nt = 0; nt < 4; nt++) {
            f32x4 acc0 = {0.f, 0.f, 0.f, 0.f};
            f32x4 acc1 = {0.f, 0.f, 0.f, 0.f};
#pragma unroll
            for (int kk = 0; kk < 2; kk++) {
                int r = nt * 16 + lo;
                int g = (kk * 4 + hi) ^ (r & 7);
                short8v ak = *(const short8v*)&Ks[bufo + r * 64 + g * 8];
                acc0 = __builtin_amdgcn_mfma_f32_16x16x32_bf16(ak, aq[0][kk], acc0, 0, 0, 0);
                acc1 = __builtin_amdgcn_mfma_f32_16x16x32_bf16(ak, aq[1][kk], acc1, 0, 0, 0);
            }
            s_acc[0][nt] = acc0;
            s_acc[1][nt] = acc1;
        }
        __builtin_amdgcn_s_setprio(0);

        // per-fragment softmax: lane-local except the rare rescale branch
        short8v pa[2][2];
#pragma unroll
        for (int qf = 0; qf < 2; qf++) {
            float t0 = max3f(s_acc[qf][0][0], s_acc[qf][0][1], s_acc[qf][0][2]);
            float t1 = max3f(s_acc[qf][0][3], s_acc[qf][1][0], s_acc[qf][1][1]);
            float t2 = max3f(s_acc[qf][1][2], s_acc[qf][1][3], s_acc[qf][2][0]);
            float t3 = max3f(s_acc[qf][2][1], s_acc[qf][2][2], s_acc[qf][2][3]);
            float t4 = max3f(s_acc[qf][3][0], s_acc[qf][3][1], s_acc[qf][3][2]);
            float lmax = fmaxf(max3f(t0, t1, t2), max3f(t3, t4, s_acc[qf][3][3]));

            if (__any(lmax > m_i[qf] + 11.0f)) {   // same predicate as row-max
                float pm = fmaxf(lmax, __shfl_xor(lmax, 16));
                pm = fmaxf(pm, __shfl_xor(pm, 32));
                float mnew = fmaxf(m_i[qf], pm);
                float al = __builtin_amdgcn_exp2f(m_i[qf] - mnew);
                m_i[qf] = mnew;
                lp[qf] *= al;
                float a0 = __shfl(al, hi * 4 + 0);
                float a1 = __shfl(al, hi * 4 + 1);
                float a2 = __shfl(al, hi * 4 + 2);
                float a3 = __shfl(al, hi * 4 + 3);
#pragma unroll
                for (int dt = 0; dt < 4; dt++) {
                    o_acc[qf][dt][0] *= a0; o_acc[qf][dt][1] *= a1;
                    o_acc[qf][dt][2] *= a2; o_acc[qf][dt][3] *= a3;
                }
            }

            float ps = 0.0f;
#pragma unroll
            for (int nt = 0; nt < 4; nt++)
#pragma unroll
                for (int reg = 0; reg < 4; reg++) {
                    s_acc[qf][nt][reg] =
                        __builtin_amdgcn_exp2f(s_acc[qf][nt][reg] - m_i[qf]);
                    ps += s_acc[qf][nt][reg];
                }
            lp[qf] += ps;   // per-lane partial; cross-lane reduce in epilogue

            int4 w0i = {(int)cvt_pk_bf16(s_acc[qf][0][0], s_acc[qf][0][1]),
                        (int)cvt_pk_bf16(s_acc[qf][0][2], s_acc[qf][0][3]),
                        (int)cvt_pk_bf16(s_acc[qf][1][0], s_acc[qf][1][1]),
                        (int)cvt_pk_bf16(s_acc[qf][1][2], s_acc[qf][1][3])};
            int4 w1i = {(int)cvt_pk_bf16(s_acc[qf][2][0], s_acc[qf][2][1]),
                        (int)cvt_pk_bf16(s_acc[qf][2][2], s_acc[qf][2][3]),
                        (int)cvt_pk_bf16(s_acc[qf][3][0], s_acc[qf][3][1]),
                        (int)cvt_pk_bf16(s_acc[qf][3][2], s_acc[qf][3][3])};
            pa[qf][0] = __builtin_bit_cast(short8v, w0i);
            pa[qf][1] = __builtin_bit_cast(short8v, w1i);
        }

        if (kt < 31) {
            const int nxto = 4096 - bufo;
            *(uint4*)&Ks[nxto + srow * 64 + sgs * 8] = rk0;
            *(uint4*)&Ks[nxto + (srow + 32) * 64 + sgs * 8] = rk1;
            uint2 va0 = {rv0.x, rv0.y}, vb0 = {rv0.z, rv0.w};
            uint2 va1 = {rv1.x, rv1.y}, vb1 = {rv1.z, rv1.w};
            *(uint2*)&Vs[nxto + srow * 64 + (gv0 ^ vswz0) * 8 + vo] = va0;
            *(uint2*)&Vs[nxto + srow * 64 + ((gv0 + 1) ^ vswz0) * 8 + vo] = vb0;
            *(uint2*)&Vs[nxto + (srow + 32) * 64 + (gv0 ^ vswz0) * 8 + vo] = va1;
            *(uint2*)&Vs[nxto + (srow + 32) * 64 + ((gv0 + 1) ^ vswz0) * 8 + vo] = vb1;
        }

        // O += P @ V. Each bv read feeds both query fragments.
        __builtin_amdgcn_s_setprio(1);
#pragma unroll
        for (int dt = 0; dt < 4; dt++) {
            int r = dt * 16 + lo;
            short8v bv0 = *(const short8v*)&Vs[bufo + r * 64 + ((0 + hi) ^ (r & 7)) * 8];
            short8v bv1 = *(const short8v*)&Vs[bufo + r * 64 + ((4 + hi) ^ (r & 7)) * 8];
            o_acc[0][dt] = __builtin_amdgcn_mfma_f32_16x16x32_bf16(pa[0][0], bv0, o_acc[0][dt], 0, 0, 0);
            o_acc[0][dt] = __builtin_amdgcn_mfma_f32_16x16x32_bf16(pa[0][1], bv1, o_acc[0][dt], 0, 0, 0);
            o_acc[1][dt] = __builtin_amdgcn_mfma_f32_16x16x32_bf16(pa[1][0], bv0, o_acc[1][dt], 0, 0, 0);
            o_acc[1][dt] = __builtin_amdgcn_mfma_f32_16x16x32_bf16(pa[1][1], bv1, o_acc[1][dt], 0, 0, 0);
        }
        __builtin_amdgcn_s_setprio(0);
        __syncthreads();
    }

    // epilogue: reduce the partial l across the 4 row-lanes, then normalize
    const int b = bh >> 4, h = bh & 15;
#pragma unroll
    for (int qf = 0; qf < 2; qf++) {
        float ls = lp[qf];
        ls += __shfl_xor(ls, 16);
        ls += __shfl_xor(ls, 32);   // full l for query qf*16+lo, all lanes
#pragma unroll
        for (int reg = 0; reg < 4; reg++) {
            float lv = __shfl(ls, hi * 4 + reg);
            float inv = 1.0f / lv;
            int row = q0 + w * 32 + qf * 16 + hi * 4 + reg;
            ushort_t* orow = O + ((size_t)(b * 2048 + row)) * 1024 + h * 64;
#pragma unroll
            for (int dt = 0; dt < 4; dt++)
                orow[dt * 16 + lo] = to_bf16(o_acc[qf][dt][reg] * inv);
        }
    }
}

extern "C" void kernel_launch(void* const* d_in, const int* in_sizes, int n_in,
                              void* d_out, int out_size, void* d_ws, size_t ws_size,
                              hipStream_t stream) {
    const float* x      = (const float*)d_in[0];
    const float* qkv_w  = (const float*)d_in[1];
    const float* qkv_b  = (const float*)d_in[2];
    const float* proj_w = (const float*)d_in[3];
    const float* proj_b = (const float*)d_in[4];
    float* out = (float*)d_out;

    ushort_t* xb  = (ushort_t*)d_ws;        // 4,194,304  x bf16
    ushort_t* wqb = xb  + 4194304;          // 3,145,728  qkv_w bf16
    ushort_t* wpb = wqb + 3145728;          // 1,048,576  proj_w bf16
    ushort_t* qb  = wpb + 1048576;          // 4,194,304  Q (exp2-scaled)
    ushort_t* kb  = qb  + 4194304;          // 4,194,304  K
    ushort_t* vt  = kb  + 4194304;          // 4,194,304  V^T [BH][64][N]
    ushort_t* aob = vt  + 4194304;          // 4,194,304  attn out [M][1024]

    convert_kernel<<<4096, 256, 0, stream>>>(x, qkv_w, proj_w, xb, wqb, wpb);
    gemm_bf16_kernel<0, 128, 128><<<768, 256, 0, stream>>>(
        xb, wqb, qkv_b, qb, kb, vt, nullptr);
    attn_mfma_kernel<<<512, 256, 0, stream>>>(qb, kb, vt, aob);
    gemm_bf16_kernel<1, 64, 128><<<dim3(8, 64), 256, 0, stream>>>(
        aob, wpb, proj_b, nullptr, nullptr, nullptr, out);
}

// Round 17
// 116.172 us; speedup vs baseline: 1.0803x; 1.0045x over previous
//
#include <hip/hip_runtime.h>
#include <hip/hip_bf16.h>
#include <math.h>

// B=2, N=2048, DIM=1024, H=16, D=64; tokens M=4096; BH=32; K=1024
typedef __attribute__((ext_vector_type(8))) short short8v;     // 8 bf16
typedef __attribute__((ext_vector_type(4))) float f32x4;
typedef unsigned short ushort_t;

__device__ __forceinline__ ushort_t to_bf16(float v) {
    __hip_bfloat16 h = __float2bfloat16(v);
    return *(ushort_t*)&h;
}

// packed f32x2 -> bf16x2 (RNE), single instruction; low half = a
__device__ __forceinline__ unsigned cvt_pk_bf16(float a, float b) {
    unsigned r;
    asm("v_cvt_pk_bf16_f32 %0, %1, %2" : "=v"(r) : "v"(a), "v"(b));
    return r;
}

// fused 3-input max (clang folds nested fmaxf to v_max3_f32)
__device__ __forceinline__ float max3f(float a, float b, float c) {
    return fmaxf(fmaxf(a, b), c);
}

__device__ __forceinline__ void load_lds_16B(const void* g, void* l) {
    __builtin_amdgcn_global_load_lds(
        (__attribute__((address_space(1))) unsigned int*)(g),
        (__attribute__((address_space(3))) unsigned int*)(l), 16, 0, 0);
}

// ---------------------------------------------------------------------------
// Fused f32 -> bf16 conversion of x (4.19M), qkv_w (3.15M), proj_w (1.05M).
// ---------------------------------------------------------------------------
__global__ __launch_bounds__(256) void convert_kernel(
    const float* __restrict__ x, const float* __restrict__ wq,
    const float* __restrict__ wp, ushort_t* __restrict__ xb,
    ushort_t* __restrict__ wqb, ushort_t* __restrict__ wpb)
{
    int c = blockIdx.x * 256 + threadIdx.x;
    const float* src; ushort_t* dst; int base;
    if (c < 524288)      { src = x;  dst = xb;  base = c; }
    else if (c < 917504) { src = wq; dst = wqb; base = c - 524288; }
    else                 { src = wp; dst = wpb; base = c - 917504; }
    const float4* s4 = (const float4*)src;
    float4 a = s4[2 * (size_t)base], b = s4[2 * (size_t)base + 1];
    float vals[8] = {a.x, a.y, a.z, a.w, b.x, b.y, b.z, b.w};
    short8v o;
#pragma unroll
    for (int j = 0; j < 8; j++) o[j] = (short)to_bf16(vals[j]);
    *(short8v*)(dst + 8 * (size_t)base) = o;
}

// ---------------------------------------------------------------------------
// bf16 MFMA GEMM, m97 structure, BK=32. MINW = declared min waves/EU
// (match the grid-limited occupancy: qkv grid 768 = 3 blocks/CU -> 3,
// proj grid 512 = 2 blocks/CU -> 2; frees the register budget the
// default max-occupancy target would reserve for waves that never come).
// MODE 0: 1D grid 768, XCD-chunked; Q(x0.125*log2e)/K/V^T scatter.
// MODE 1: 2D grid; f32 C = A @ W^T + bias.
// ---------------------------------------------------------------------------
template <int MODE, int BM, int BN, int MINW>
__global__ __launch_bounds__(256, MINW) void gemm_bf16_kernel(
    const ushort_t* __restrict__ A, const ushort_t* __restrict__ Bw,
    const float* __restrict__ bias, ushort_t* __restrict__ Qb,
    ushort_t* __restrict__ Kb, ushort_t* __restrict__ Vt,
    float* __restrict__ Cout)
{
    constexpr int MT = BM / 32, NT = BN / 32;
    __shared__ __align__(16) ushort_t As[BM * 32];
    __shared__ __align__(16) ushort_t Bs[BN * 32];
    const int t = threadIdx.x;
    const int w = t >> 6, l = t & 63;
    const int lo = l & 15, hi = l >> 4;
    const int wr = w >> 1, wc = w & 1;
    int m0, n0;
    if constexpr (MODE == 0) {
        // bijective XCD chunking: 768 blocks = 8 XCDs x 96
        int lin = (blockIdx.x & 7) * 96 + (blockIdx.x >> 3);
        m0 = (lin / 24) * BM;
        n0 = (lin % 24) * BN;
    } else {
        m0 = blockIdx.y * BM;
        n0 = blockIdx.x * BN;
    }
    const int K = 1024;

    const ushort_t* ga = A + (size_t)(m0 + (t >> 2)) * K + (t & 3) * 8;
    const ushort_t* gb = Bw + (size_t)(n0 + (t >> 2)) * K + (t & 3) * 8;

    f32x4 acc[MT][NT] = {};

    for (int k0 = 0; k0 < 1024; k0 += 32) {
#pragma unroll
        for (int i = 0; i < BM / 64; i++)
            load_lds_16B(ga + (size_t)(i * 64) * K + k0, As + (i * 256 + w * 64) * 8);
#pragma unroll
        for (int i = 0; i < BN / 64; i++)
            load_lds_16B(gb + (size_t)(i * 64) * K + k0, Bs + (i * 256 + w * 64) * 8);
        __syncthreads();

        short8v af[MT], bf[NT];
#pragma unroll
        for (int mt = 0; mt < MT; mt++) {
            int r = wr * (BM / 2) + mt * 16 + lo;
            af[mt] = *(const short8v*)&As[r * 32 + hi * 8];
        }
#pragma unroll
        for (int nt = 0; nt < NT; nt++) {
            int r = wc * (BN / 2) + nt * 16 + lo;
            bf[nt] = *(const short8v*)&Bs[r * 32 + hi * 8];
        }
#pragma unroll
        for (int mt = 0; mt < MT; mt++)
#pragma unroll
            for (int nt = 0; nt < NT; nt++)
                acc[mt][nt] = __builtin_amdgcn_mfma_f32_16x16x32_bf16(
                    af[mt], bf[nt], acc[mt][nt], 0, 0, 0);
        __syncthreads();
    }

#pragma unroll
    for (int mt = 0; mt < MT; mt++) {
#pragma unroll
        for (int nt = 0; nt < NT; nt++) {
            int col = n0 + wc * (BN / 2) + nt * 16 + lo;
            float bv = bias[col];
#pragma unroll
            for (int reg = 0; reg < 4; reg++) {
                int row = m0 + wr * (BM / 2) + mt * 16 + hi * 4 + reg;
                float val = acc[mt][nt][reg] + bv;
                if constexpr (MODE == 0) {
                    int bb = row >> 11, n = row & 2047;
                    int which = col >> 10, rem = col & 1023;
                    int h = rem >> 6, d = rem & 63;
                    int bh = bb * 16 + h;
                    if (which == 0)  // 0.125 * log2(e): softmax in exp2 domain
                        Qb[((size_t)bh * 2048 + n) * 64 + d] = to_bf16(val * 0.1803368601f);
                    else if (which == 1)
                        Kb[((size_t)bh * 2048 + n) * 64 + d] = to_bf16(val);
                    else
                        Vt[((size_t)bh * 64 + d) * 2048 + n] = to_bf16(val);
                } else {
                    Cout[(size_t)row * 1024 + col] = val;
                }
            }
        }
    }
}

// ---------------------------------------------------------------------------
// MFMA flash attention v8c (verified round-16): v8b + __launch_bounds__(256,2).
// grid = 512 (XCD-swizzled), 4 waves x 32 q-rows (2 Q fragments/wave).
// Deferred-l, branch-gated rescale, P in registers, permuted-column V,
// reg-staged K/V dbuf + async-stage, 1 barrier/tile, max3 fmax tree.
// ---------------------------------------------------------------------------
__global__ __launch_bounds__(256, 2) void attn_mfma_kernel(
    const ushort_t* __restrict__ Qg0, const ushort_t* __restrict__ Kg0,
    const ushort_t* __restrict__ Vg0, ushort_t* __restrict__ O)
{
    __shared__ __align__(16) ushort_t Ks[2 * 4096];  // [buf][key][d] swz
    __shared__ __align__(16) ushort_t Vs[2 * 4096];  // [buf][d][permuted k]

    const int t = threadIdx.x;
    const int l = t & 63, w = t >> 6;
    const int lo = l & 15, hi = l >> 4;
    const int lin = (blockIdx.x & 7) * 64 + (blockIdx.x >> 3);
    const int bh = lin >> 4;
    const int q0 = (lin & 15) * 128;
    const ushort_t* Qg = Qg0 + (size_t)bh * 2048 * 64;
    const ushort_t* Kg = Kg0 + (size_t)bh * 2048 * 64;
    const ushort_t* Vg = Vg0 + (size_t)bh * 64 * 2048;

    // Q B-fragments: wave covers queries q0 + w*32 + qf*16 + lo
    short8v aq[2][2];
#pragma unroll
    for (int qf = 0; qf < 2; qf++) {
        const ushort_t* qrow = Qg + (size_t)(q0 + w * 32 + qf * 16 + lo) * 64;
        aq[qf][0] = *(const short8v*)(qrow + hi * 8);
        aq[qf][1] = *(const short8v*)(qrow + 32 + hi * 8);
    }

    const int srow = t >> 3, sg = t & 7;
    const int sgs = sg ^ (srow & 7);
    const int gv0 = (sg >> 2) * 4 + (sg & 1) * 2;
    const int vo = ((sg >> 1) & 1) * 4;
    const int vswz0 = srow & 7;
    uint4 rk0, rk1, rv0, rv1;

    f32x4 o_acc[2][4] = {};
    float m_i[2] = {-INFINITY, -INFINITY};
    float lp[2] = {0.0f, 0.0f};   // per-lane PARTIAL l (own 16 keys)

    {
        rk0 = *(const uint4*)(Kg + (size_t)srow * 64 + sg * 8);
        rk1 = *(const uint4*)(Kg + (size_t)(srow + 32) * 64 + sg * 8);
        rv0 = *(const uint4*)(Vg + (size_t)srow * 2048 + sg * 8);
        rv1 = *(const uint4*)(Vg + (size_t)(srow + 32) * 2048 + sg * 8);
        *(uint4*)&Ks[srow * 64 + sgs * 8] = rk0;
        *(uint4*)&Ks[(srow + 32) * 64 + sgs * 8] = rk1;
        uint2 va0 = {rv0.x, rv0.y}, vb0 = {rv0.z, rv0.w};
        uint2 va1 = {rv1.x, rv1.y}, vb1 = {rv1.z, rv1.w};
        *(uint2*)&Vs[srow * 64 + (gv0 ^ vswz0) * 8 + vo] = va0;
        *(uint2*)&Vs[srow * 64 + ((gv0 + 1) ^ vswz0) * 8 + vo] = vb0;
        *(uint2*)&Vs[(srow + 32) * 64 + (gv0 ^ vswz0) * 8 + vo] = va1;
        *(uint2*)&Vs[(srow + 32) * 64 + ((gv0 + 1) ^ vswz0) * 8 + vo] = vb1;
    }
    __syncthreads();

    for (int kt = 0; kt < 32; kt++) {
        const int bufo = (kt & 1) * 4096;
        if (kt < 31) {
            const int k0n = (kt + 1) * 64;
            rk0 = *(const uint4*)(Kg + (size_t)(k0n + srow) * 64 + sg * 8);
            rk1 = *(const uint4*)(Kg + (size_t)(k0n + srow + 32) * 64 + sg * 8);
            rv0 = *(const uint4*)(Vg + (size_t)srow * 2048 + k0n + sg * 8);
            rv1 = *(const uint4*)(Vg + (size_t)(srow + 32) * 2048 + k0n + sg * 8);
        }

        // S^T = K @ Q^T : lane owns query qf*16+lo; keys nt*16 + hi*4 + reg.
        f32x4 s_acc[2][4];
        __builtin_amdgcn_s_setprio(1);
#pragma unroll
        for (int nt = 0; nt < 4; nt++) {
            f32x4 acc0 = {0.f, 0.f, 0.f, 0.f};
            f32x4 acc1 = {0.f, 0.f, 0.f, 0.f};
#pragma unroll
            for (int kk = 0; kk < 2; kk++) {
                int r = nt * 16 + lo;
                int g = (kk * 4 + hi) ^ (r & 7);
                short8v ak = *(const short8v*)&Ks[bufo + r * 64 + g * 8];
                acc0 = __builtin_amdgcn_mfma_f32_16x16x32_bf16(ak, aq[0][kk], acc0, 0, 0, 0);
                acc1 = __builtin_amdgcn_mfma_f32_16x16x32_bf16(ak, aq[1][kk], acc1, 0, 0, 0);
            }
            s_acc[0][nt] = acc0;
            s_acc[1][nt] = acc1;
        }
        __builtin_amdgcn_s_setprio(0);

        // per-fragment softmax: lane-local except the rare rescale branch
        short8v pa[2][2];
#pragma unroll
        for (int qf = 0; qf < 2; qf++) {
            float t0 = max3f(s_acc[qf][0][0], s_acc[qf][0][1], s_acc[qf][0][2]);
            float t1 = max3f(s_acc[qf][0][3], s_acc[qf][1][0], s_acc[qf][1][1]);
            float t2 = max3f(s_acc[qf][1][2], s_acc[qf][1][3], s_acc[qf][2][0]);
            float t3 = max3f(s_acc[qf][2][1], s_acc[qf][2][2], s_acc[qf][2][3]);
            float t4 = max3f(s_acc[qf][3][0], s_acc[qf][3][1], s_acc[qf][3][2]);
            float lmax = fmaxf(max3f(t0, t1, t2), max3f(t3, t4, s_acc[qf][3][3]));

            if (__any(lmax > m_i[qf] + 11.0f)) {   // same predicate as row-max
                float pm = fmaxf(lmax, __shfl_xor(lmax, 16));
                pm = fmaxf(pm, __shfl_xor(pm, 32));
                float mnew = fmaxf(m_i[qf], pm);
                float al = __builtin_amdgcn_exp2f(m_i[qf] - mnew);
                m_i[qf] = mnew;
                lp[qf] *= al;
                float a0 = __shfl(al, hi * 4 + 0);
                float a1 = __shfl(al, hi * 4 + 1);
                float a2 = __shfl(al, hi * 4 + 2);
                float a3 = __shfl(al, hi * 4 + 3);
#pragma unroll
                for (int dt = 0; dt < 4; dt++) {
                    o_acc[qf][dt][0] *= a0; o_acc[qf][dt][1] *= a1;
                    o_acc[qf][dt][2] *= a2; o_acc[qf][dt][3] *= a3;
                }
            }

            float ps = 0.0f;
#pragma unroll
            for (int nt = 0; nt < 4; nt++)
#pragma unroll
                for (int reg = 0; reg < 4; reg++) {
                    s_acc[qf][nt][reg] =
                        __builtin_amdgcn_exp2f(s_acc[qf][nt][reg] - m_i[qf]);
                    ps += s_acc[qf][nt][reg];
                }
            lp[qf] += ps;   // per-lane partial; cross-lane reduce in epilogue

            int4 w0i = {(int)cvt_pk_bf16(s_acc[qf][0][0], s_acc[qf][0][1]),
                        (int)cvt_pk_bf16(s_acc[qf][0][2], s_acc[qf][0][3]),
                        (int)cvt_pk_bf16(s_acc[qf][1][0], s_acc[qf][1][1]),
                        (int)cvt_pk_bf16(s_acc[qf][1][2], s_acc[qf][1][3])};
            int4 w1i = {(int)cvt_pk_bf16(s_acc[qf][2][0], s_acc[qf][2][1]),
                        (int)cvt_pk_bf16(s_acc[qf][2][2], s_acc[qf][2][3]),
                        (int)cvt_pk_bf16(s_acc[qf][3][0], s_acc[qf][3][1]),
                        (int)cvt_pk_bf16(s_acc[qf][3][2], s_acc[qf][3][3])};
            pa[qf][0] = __builtin_bit_cast(short8v, w0i);
            pa[qf][1] = __builtin_bit_cast(short8v, w1i);
        }

        if (kt < 31) {
            const int nxto = 4096 - bufo;
            *(uint4*)&Ks[nxto + srow * 64 + sgs * 8] = rk0;
            *(uint4*)&Ks[nxto + (srow + 32) * 64 + sgs * 8] = rk1;
            uint2 va0 = {rv0.x, rv0.y}, vb0 = {rv0.z, rv0.w};
            uint2 va1 = {rv1.x, rv1.y}, vb1 = {rv1.z, rv1.w};
            *(uint2*)&Vs[nxto + srow * 64 + (gv0 ^ vswz0) * 8 + vo] = va0;
            *(uint2*)&Vs[nxto + srow * 64 + ((gv0 + 1) ^ vswz0) * 8 + vo] = vb0;
            *(uint2*)&Vs[nxto + (srow + 32) * 64 + (gv0 ^ vswz0) * 8 + vo] = va1;
            *(uint2*)&Vs[nxto + (srow + 32) * 64 + ((gv0 + 1) ^ vswz0) * 8 + vo] = vb1;
        }

        // O += P @ V. Each bv read feeds both query fragments.
        __builtin_amdgcn_s_setprio(1);
#pragma unroll
        for (int dt = 0; dt < 4; dt++) {
            int r = dt * 16 + lo;
            short8v bv0 = *(const short8v*)&Vs[bufo + r * 64 + ((0 + hi) ^ (r & 7)) * 8];
            short8v bv1 = *(const short8v*)&Vs[bufo + r * 64 + ((4 + hi) ^ (r & 7)) * 8];
            o_acc[0][dt] = __builtin_amdgcn_mfma_f32_16x16x32_bf16(pa[0][0], bv0, o_acc[0][dt], 0, 0, 0);
            o_acc[0][dt] = __builtin_amdgcn_mfma_f32_16x16x32_bf16(pa[0][1], bv1, o_acc[0][dt], 0, 0, 0);
            o_acc[1][dt] = __builtin_amdgcn_mfma_f32_16x16x32_bf16(pa[1][0], bv0, o_acc[1][dt], 0, 0, 0);
            o_acc[1][dt] = __builtin_amdgcn_mfma_f32_16x16x32_bf16(pa[1][1], bv1, o_acc[1][dt], 0, 0, 0);
        }
        __builtin_amdgcn_s_setprio(0);
        __syncthreads();
    }

    // epilogue: reduce the partial l across the 4 row-lanes, then normalize
    const int b = bh >> 4, h = bh & 15;
#pragma unroll
    for (int qf = 0; qf < 2; qf++) {
        float ls = lp[qf];
        ls += __shfl_xor(ls, 16);
        ls += __shfl_xor(ls, 32);   // full l for query qf*16+lo, all lanes
#pragma unroll
        for (int reg = 0; reg < 4; reg++) {
            float lv = __shfl(ls, hi * 4 + reg);
            float inv = 1.0f / lv;
            int row = q0 + w * 32 + qf * 16 + hi * 4 + reg;
            ushort_t* orow = O + ((size_t)(b * 2048 + row)) * 1024 + h * 64;
#pragma unroll
            for (int dt = 0; dt < 4; dt++)
                orow[dt * 16 + lo] = to_bf16(o_acc[qf][dt][reg] * inv);
        }
    }
}

extern "C" void kernel_launch(void* const* d_in, const int* in_sizes, int n_in,
                              void* d_out, int out_size, void* d_ws, size_t ws_size,
                              hipStream_t stream) {
    const float* x      = (const float*)d_in[0];
    const float* qkv_w  = (const float*)d_in[1];
    const float* qkv_b  = (const float*)d_in[2];
    const float* proj_w = (const float*)d_in[3];
    const float* proj_b = (const float*)d_in[4];
    float* out = (float*)d_out;

    ushort_t* xb  = (ushort_t*)d_ws;        // 4,194,304  x bf16
    ushort_t* wqb = xb  + 4194304;          // 3,145,728  qkv_w bf16
    ushort_t* wpb = wqb + 3145728;          // 1,048,576  proj_w bf16
    ushort_t* qb  = wpb + 1048576;          // 4,194,304  Q (exp2-scaled)
    ushort_t* kb  = qb  + 4194304;          // 4,194,304  K
    ushort_t* vt  = kb  + 4194304;          // 4,194,304  V^T [BH][64][N]
    ushort_t* aob = vt  + 4194304;          // 4,194,304  attn out [M][1024]

    convert_kernel<<<4096, 256, 0, stream>>>(x, qkv_w, proj_w, xb, wqb, wpb);
    gemm_bf16_kernel<0, 128, 128, 3><<<768, 256, 0, stream>>>(
        xb, wqb, qkv_b, qb, kb, vt, nullptr);
    attn_mfma_kernel<<<512, 256, 0, stream>>>(qb, kb, vt, aob);
    gemm_bf16_kernel<1, 64, 128, 2><<<dim3(8, 64), 256, 0, stream>>>(
        aob, wpb, proj_b, nullptr, nullptr, nullptr, out);
}